// Round 2
// baseline (60.498 us; speedup 1.0000x reference)
//
#include <hip/hip_runtime.h>

#define MXN 2048   // MX == NY == 2048
#define DD  256
#define KK  100
#define KP  128    // K padded to MFMA granularity
#define NB  8

typedef __attribute__((ext_vector_type(8))) __bf16 bf16x8;
typedef __attribute__((ext_vector_type(4))) float  f32x4;

__device__ __forceinline__ unsigned short f2b(float f) {
  union { float f; unsigned u; } v; v.f = f;
  return (unsigned short)((v.u + 0x7fffu + ((v.u >> 16) & 1u)) >> 16);
}
__device__ __forceinline__ float b2f(unsigned short h) {
  union { unsigned u; float f; } v; v.u = ((unsigned)h) << 16;
  return v.f;
}

// ---------------------------------------------------------------------------
// Kernel 0: At[k][d] = bf16(A[d][k]), zero-padded for k in [100,128).
// 64 KB table, stays L2-hot for k_proj.
// ---------------------------------------------------------------------------
__global__ __launch_bounds__(256) void k_At(const float* __restrict__ A,
                                            unsigned short* __restrict__ At) {
  int idx = blockIdx.x * 256 + threadIdx.x;   // 0 .. 128*256-1
  int k = idx >> 8, d = idx & 255;
  At[idx] = (k < KK) ? f2b(A[d * KK + k]) : (unsigned short)0;
}

// ---------------------------------------------------------------------------
// Kernel 1 (LDS-free): XA = bf16(X @ A), sqX[r] = sum_k XA[r][k]^2.
// 512 blocks: bid<256 -> X rows, bid>=256 -> Y rows. 64 rows/block,
// 4 waves x 16 rows. A-operand fragments loaded straight from global f32
// (2x float4 + in-register bf16 convert); B-operand fragments from At (L2).
// ---------------------------------------------------------------------------
__global__ __launch_bounds__(256) void k_proj(
    const float* __restrict__ X, const float* __restrict__ Y,
    const unsigned short* __restrict__ At,
    unsigned short* __restrict__ XAo, unsigned short* __restrict__ YAo,
    float* __restrict__ sqX, float* __restrict__ sqY)
{
  const int bid = blockIdx.x;
  const bool isY = bid >= 256;
  const int row0 = (bid & 255) * 64;
  const float* __restrict__ src = isY ? Y : X;
  unsigned short* __restrict__ dst = isY ? YAo : XAo;
  float* __restrict__ sqdst = isY ? sqY : sqX;

  const int t = threadIdx.x;
  const int w = t >> 6, l = t & 63;
  const int lr = l & 15, lk8 = (l >> 4) * 8;
  const int rowA = row0 + w * 16 + lr;          // this lane's A-operand row

  f32x4 acc[8];
#pragma unroll
  for (int j = 0; j < 8; ++j) acc[j] = (f32x4){0.f, 0.f, 0.f, 0.f};

#pragma unroll
  for (int ks = 0; ks < 8; ++ks) {
    const int d = ks * 32 + lk8;
    const float* px = src + (size_t)rowA * DD + d;
    float4 v0 = *reinterpret_cast<const float4*>(px);
    float4 v1 = *reinterpret_cast<const float4*>(px + 4);
    bf16x8 af;
    {
      union { bf16x8 v; unsigned short u[8]; } cv;
      cv.u[0] = f2b(v0.x); cv.u[1] = f2b(v0.y); cv.u[2] = f2b(v0.z); cv.u[3] = f2b(v0.w);
      cv.u[4] = f2b(v1.x); cv.u[5] = f2b(v1.y); cv.u[6] = f2b(v1.z); cv.u[7] = f2b(v1.w);
      af = cv.v;
    }
#pragma unroll
    for (int nf = 0; nf < 8; ++nf) {
      const int kq = nf * 16 + lr;
      bf16x8 bf = *reinterpret_cast<const bf16x8*>(At + kq * DD + d);
      acc[nf] = __builtin_amdgcn_mfma_f32_16x16x32_bf16(af, bf, acc[nf], 0, 0, 0);
    }
  }

  // Epilogue: quantize, store XA row-major [r][k], accumulate row ||.||^2.
  float sq[4] = {0.f, 0.f, 0.f, 0.f};
#pragma unroll
  for (int nf = 0; nf < 8; ++nf)
#pragma unroll
    for (int reg = 0; reg < 4; ++reg) {
      float v = acc[nf][reg];
      unsigned short h = f2b(v);
      float vq = b2f(h);
      int r = row0 + w * 16 + ((l >> 4) << 2) + reg;
      dst[(size_t)r * KP + nf * 16 + lr] = h;
      sq[reg] += vq * vq;
    }
#pragma unroll
  for (int reg = 0; reg < 4; ++reg) {
    float s = sq[reg];
    s += __shfl_xor(s, 1);
    s += __shfl_xor(s, 2);
    s += __shfl_xor(s, 4);
    s += __shfl_xor(s, 8);
    if (lr == 0)
      sqdst[row0 + w * 16 + ((l >> 4) << 2) + reg] = s;
  }
}

// ---------------------------------------------------------------------------
// Kernel 2: out[b][n][m] = relu(sqY[n] + sqX[m] - 2 * sum_k YA[n][k]*XA[m][k])
// 128x128 tile per block; 4 waves each 64x64; K = 128 (4 MFMA steps).
// XCD swizzle: b = bid & 7 pins each batch's 1 MB XA/YA set to one XCD's L2.
// ---------------------------------------------------------------------------
__global__ __launch_bounds__(256) void k_cross(
    const unsigned short* __restrict__ XA, const unsigned short* __restrict__ YA,
    const float* __restrict__ sqX, const float* __restrict__ sqY,
    float* __restrict__ out)
{
  __shared__ __align__(16) unsigned short Ysh[128 * 128]; // [n][k], swizzled, 32 KB
  __shared__ __align__(16) unsigned short Xsh[128 * 128]; // [m][k], swizzled, 32 KB

  const int bid = blockIdx.x;
  const int b  = bid & 7;           // batch -> XCD (round-robin dispatch)
  const int tb = bid >> 3;          // 0..255 tile within batch
  const int n0 = (tb >> 4) * 128;
  const int m0 = (tb & 15) * 128;
  const int t = threadIdx.x;

#pragma unroll
  for (int i = 0; i < 8; ++i) {
    int ch = i * 256 + t;           // 16 chunks of 8 bf16 per row
    int row = ch >> 4, c = ch & 15;
    bf16x8 vy = *reinterpret_cast<const bf16x8*>(YA + ((size_t)(b * MXN + n0 + row) * KP + c * 8));
    bf16x8 vx = *reinterpret_cast<const bf16x8*>(XA + ((size_t)(b * MXN + m0 + row) * KP + c * 8));
    int byte = (row * 256 + c * 16) ^ ((row & 7) << 4);
    *reinterpret_cast<bf16x8*>((char*)Ysh + byte) = vy;
    *reinterpret_cast<bf16x8*>((char*)Xsh + byte) = vx;
  }
  __syncthreads();

  const int w  = t >> 6, l = t & 63;
  const int nr0 = (w & 1) * 64;     // wave's n-offset within tile
  const int mc0 = (w >> 1) * 64;    // wave's m-offset within tile
  const int lr = l & 15, lk = (l >> 4) * 8;

  f32x4 acc[4][4];
#pragma unroll
  for (int i = 0; i < 4; ++i)
#pragma unroll
    for (int j = 0; j < 4; ++j) acc[i][j] = (f32x4){0.f, 0.f, 0.f, 0.f};

#pragma unroll
  for (int ks = 0; ks < 4; ++ks) {
    const int d = ks * 32 + lk;
    bf16x8 afr[4], bfr[4];
#pragma unroll
    for (int i = 0; i < 4; ++i) {
      int rn = nr0 + i * 16 + lr;
      afr[i] = *reinterpret_cast<bf16x8*>((char*)Ysh + ((rn * 256 + d * 2) ^ ((rn & 7) << 4)));
      int rm = mc0 + i * 16 + lr;
      bfr[i] = *reinterpret_cast<bf16x8*>((char*)Xsh + ((rm * 256 + d * 2) ^ ((rm & 7) << 4)));
    }
#pragma unroll
    for (int i = 0; i < 4; ++i)
#pragma unroll
      for (int j = 0; j < 4; ++j)
        acc[i][j] = __builtin_amdgcn_mfma_f32_16x16x32_bf16(afr[i], bfr[j], acc[i][j], 0, 0, 0);
  }

  float sx[4];
#pragma unroll
  for (int j = 0; j < 4; ++j) sx[j] = sqX[b * MXN + m0 + mc0 + j * 16 + lr];

#pragma unroll
  for (int i = 0; i < 4; ++i)
#pragma unroll
    for (int reg = 0; reg < 4; ++reg) {
      int n = n0 + nr0 + i * 16 + ((l >> 4) << 2) + reg;
      float sy = sqY[b * MXN + n];
      size_t obase = ((size_t)b * MXN + n) * MXN + m0 + mc0;
#pragma unroll
      for (int j = 0; j < 4; ++j) {
        float v = sy + sx[j] - 2.0f * acc[i][j][reg];
        out[obase + j * 16 + lr] = v > 0.f ? v : 0.f;
      }
    }
}

extern "C" void kernel_launch(void* const* d_in, const int* in_sizes, int n_in,
                              void* d_out, int out_size, void* d_ws, size_t ws_size,
                              hipStream_t stream) {
  const float* X = (const float*)d_in[0];   // (8, 2048, 256)
  const float* Y = (const float*)d_in[1];   // (8, 2048, 256)
  const float* A = (const float*)d_in[2];   // (256, 100)
  float* out = (float*)d_out;               // (8, 2048, 2048)

  char* ws = (char*)d_ws;
  const size_t ROWS = (size_t)NB * MXN;     // 16384
  unsigned short* XAw = (unsigned short*)ws;                        // 4 MB
  unsigned short* YAw = (unsigned short*)(ws + ROWS * KP * 2);      // 4 MB
  float* sqX = (float*)(ws + 2 * ROWS * KP * 2);                    // 64 KB
  float* sqY = (float*)(ws + 2 * ROWS * KP * 2 + ROWS * 4);         // 64 KB
  unsigned short* At = (unsigned short*)(ws + 2 * ROWS * KP * 2 + 2 * ROWS * 4); // 64 KB

  k_At  <<<128, 256, 0, stream>>>(A, At);
  k_proj<<<512, 256, 0, stream>>>(X, Y, At, XAw, YAw, sqX, sqY);
  k_cross<<<NB * 256, 256, 0, stream>>>(XAw, YAw, sqX, sqY, out);
}

// Round 3
// 47.197 us; speedup vs baseline: 1.2818x; 1.2818x over previous
//
#include <hip/hip_runtime.h>

#define MXN 2048   // MX == NY == 2048
#define DD  256
#define KK  100
#define KP  128    // K padded to MFMA granularity
#define NB  8

typedef __attribute__((ext_vector_type(8))) __bf16 bf16x8;
typedef __attribute__((ext_vector_type(4))) float  f32x4;

__device__ __forceinline__ unsigned short f2b(float f) {
  union { float f; unsigned u; } v; v.f = f;
  return (unsigned short)((v.u + 0x7fffu + ((v.u >> 16) & 1u)) >> 16);
}
__device__ __forceinline__ float b2f(unsigned short h) {
  union { unsigned u; float f; } v; v.u = ((unsigned)h) << 16;
  return v.f;
}

// ---------------------------------------------------------------------------
// Kernel 0: At[k][d] = bf16(A[d][k]), zero-padded for k in [100,128). 64 KB.
// ---------------------------------------------------------------------------
__global__ __launch_bounds__(256) void k_At(const float* __restrict__ A,
                                            unsigned short* __restrict__ At) {
  int idx = blockIdx.x * 256 + threadIdx.x;   // 0 .. 128*256-1
  int k = idx >> 8, d = idx & 255;
  At[idx] = (k < KK) ? f2b(A[d * KK + k]) : (unsigned short)0;
}

// ---------------------------------------------------------------------------
// Kernel 1: XA = bf16(X @ A), sqX[r] = sum_k XA[r][k]^2.
// 512 blocks x 256 thr; bid<256 -> X, else Y; 64 rows/block, 4 waves x 16 rows.
// B-operand: At staged once into 64 KB swizzled LDS (16 coalesced b128 writes).
// A-operand: X loaded direct from global f32 (per-row 128 B groups), converted
// in-register.
// ---------------------------------------------------------------------------
__global__ __launch_bounds__(256) void k_proj(
    const float* __restrict__ X, const float* __restrict__ Y,
    const unsigned short* __restrict__ At,
    unsigned short* __restrict__ XAo, unsigned short* __restrict__ YAo,
    float* __restrict__ sqX, float* __restrict__ sqY)
{
  __shared__ __align__(16) unsigned short Ash[128 * 256]; // [k][d] swizzled, 64 KB

  const int bid = blockIdx.x;
  const bool isY = bid >= 256;
  const int row0 = (bid & 255) * 64;
  const float* __restrict__ src = isY ? Y : X;
  unsigned short* __restrict__ dst = isY ? YAo : XAo;
  float* __restrict__ sqdst = isY ? sqY : sqX;
  const int t = threadIdx.x;

  // Stage At (64 KB): 4096 16B-chunks; chunk ch -> row k = ch>>5, col c = ch&31.
#pragma unroll
  for (int i = 0; i < 16; ++i) {
    int ch = i * 256 + t;
    int row = ch >> 5, c = ch & 31;
    bf16x8 v = *reinterpret_cast<const bf16x8*>(At + ch * 8);
    int byte = (row * 512 + c * 16) ^ ((row & 7) << 4);
    *reinterpret_cast<bf16x8*>((char*)Ash + byte) = v;
  }
  __syncthreads();

  const int w = t >> 6, l = t & 63;
  const int lr = l & 15, lk8 = (l >> 4) * 8;
  const int rowA = row0 + w * 16 + lr;          // this lane's A-operand row

  f32x4 acc[8];
#pragma unroll
  for (int j = 0; j < 8; ++j) acc[j] = (f32x4){0.f, 0.f, 0.f, 0.f};

#pragma unroll
  for (int ks = 0; ks < 8; ++ks) {
    const int d = ks * 32 + lk8;
    const float* px = src + (size_t)rowA * DD + d;
    float4 v0 = *reinterpret_cast<const float4*>(px);
    float4 v1 = *reinterpret_cast<const float4*>(px + 4);
    bf16x8 af;
    {
      union { bf16x8 v; unsigned short u[8]; } cv;
      cv.u[0] = f2b(v0.x); cv.u[1] = f2b(v0.y); cv.u[2] = f2b(v0.z); cv.u[3] = f2b(v0.w);
      cv.u[4] = f2b(v1.x); cv.u[5] = f2b(v1.y); cv.u[6] = f2b(v1.z); cv.u[7] = f2b(v1.w);
      af = cv.v;
    }
#pragma unroll
    for (int nf = 0; nf < 8; ++nf) {
      const int kq = nf * 16 + lr;
      bf16x8 bf = *reinterpret_cast<bf16x8*>(
          (char*)Ash + ((kq * 512 + d * 2) ^ ((kq & 7) << 4)));
      acc[nf] = __builtin_amdgcn_mfma_f32_16x16x32_bf16(af, bf, acc[nf], 0, 0, 0);
    }
  }

  // Epilogue: quantize, store XA row-major [r][KP], accumulate row ||.||^2.
  float sq[4] = {0.f, 0.f, 0.f, 0.f};
#pragma unroll
  for (int nf = 0; nf < 8; ++nf)
#pragma unroll
    for (int reg = 0; reg < 4; ++reg) {
      float v = acc[nf][reg];
      unsigned short h = f2b(v);
      float vq = b2f(h);
      int r = row0 + w * 16 + ((l >> 4) << 2) + reg;
      dst[(size_t)r * KP + nf * 16 + lr] = h;
      sq[reg] += vq * vq;
    }
#pragma unroll
  for (int reg = 0; reg < 4; ++reg) {
    float s = sq[reg];
    s += __shfl_xor(s, 1);
    s += __shfl_xor(s, 2);
    s += __shfl_xor(s, 4);
    s += __shfl_xor(s, 8);
    if (lr == 0)
      sqdst[row0 + w * 16 + ((l >> 4) << 2) + reg] = s;
  }
}

// ---------------------------------------------------------------------------
// Kernel 2: out[b][n][m] = relu(sqY[n] + sqX[m] - 2 * sum_k YA[n][k]*XA[m][k])
// Strip-persistent: block owns batch b (= bid&7, XCD-pinned) and a 32-row
// n-strip; loops all 16 m-tiles of 128. Ysh (8 KB) staged once; Xsh
// double-buffered 2x32 KB, next tile's loads issued before compute (T14),
// one barrier per tile. 512 blocks x 256 thr = exactly 2 blocks/CU.
// ---------------------------------------------------------------------------
__global__ __launch_bounds__(256) void k_cross(
    const unsigned short* __restrict__ XA, const unsigned short* __restrict__ YA,
    const float* __restrict__ sqX, const float* __restrict__ sqY,
    float* __restrict__ out)
{
  __shared__ __align__(16) unsigned short Ysh[32 * 128];      // 8 KB swizzled
  __shared__ __align__(16) unsigned short Xsh[2][128 * 128];  // 2x32 KB swizzled

  const int bid = blockIdx.x;
  const int b  = bid & 7;           // batch -> XCD pin
  const int n0 = (bid >> 3) * 32;   // 64 strips per batch
  const int t = threadIdx.x;

  // Stage Ysh: 512 chunks of 16B.
#pragma unroll
  for (int i = 0; i < 2; ++i) {
    int ch = i * 256 + t;
    int row = ch >> 4, c = ch & 15;
    bf16x8 vy = *reinterpret_cast<const bf16x8*>(
        YA + ((size_t)(b * MXN + n0 + row) * KP + c * 8));
    int byte = (row * 256 + c * 16) ^ ((row & 7) << 4);
    *reinterpret_cast<bf16x8*>((char*)Ysh + byte) = vy;
  }

  // Preload m-tile 0 into regs, write Xsh[0].
  bf16x8 xr[8];
#pragma unroll
  for (int i = 0; i < 8; ++i) {
    int ch = i * 256 + t;
    int row = ch >> 4, c = ch & 15;
    xr[i] = *reinterpret_cast<const bf16x8*>(
        XA + ((size_t)(b * MXN + row) * KP + c * 8));
  }
#pragma unroll
  for (int i = 0; i < 8; ++i) {
    int ch = i * 256 + t;
    int row = ch >> 4, c = ch & 15;
    int byte = (row * 256 + c * 16) ^ ((row & 7) << 4);
    *reinterpret_cast<bf16x8*>((char*)Xsh[0] + byte) = xr[i];
  }

  const int w = t >> 6, l = t & 63;
  const int m_w = w * 32;           // wave's m-offset within the 128-tile
  const int lr = l & 15, lk = (l >> 4) * 8;

  // Preload this lane's 8 sqY values (n rows it writes).
  float syv[2][4];
#pragma unroll
  for (int i = 0; i < 2; ++i)
#pragma unroll
    for (int reg = 0; reg < 4; ++reg)
      syv[i][reg] = sqY[b * MXN + n0 + i * 16 + ((l >> 4) << 2) + reg];

  int cur = 0;
  for (int mt = 0; mt < 16; ++mt) {
    __syncthreads();                 // Xsh[cur] ready; prev readers done

    // Issue next tile's global loads early (latency hides under compute).
    if (mt < 15) {
#pragma unroll
      for (int i = 0; i < 8; ++i) {
        int ch = i * 256 + t;
        int row = ch >> 4, c = ch & 15;
        xr[i] = *reinterpret_cast<const bf16x8*>(
            XA + ((size_t)(b * MXN + (mt + 1) * 128 + row) * KP + c * 8));
      }
    }

    // Compute 32n x 32m per wave: 2x2 frags, K = 128 in 4 steps.
    f32x4 acc[2][2];
#pragma unroll
    for (int i = 0; i < 2; ++i)
#pragma unroll
      for (int j = 0; j < 2; ++j) acc[i][j] = (f32x4){0.f, 0.f, 0.f, 0.f};

#pragma unroll
    for (int ks = 0; ks < 4; ++ks) {
      const int d2 = ks * 64 + lk * 2;   // byte offset within row
      int rn0 = lr, rn1 = 16 + lr;
      bf16x8 a0 = *reinterpret_cast<bf16x8*>(
          (char*)Ysh + ((rn0 * 256 + d2) ^ ((rn0 & 7) << 4)));
      bf16x8 a1 = *reinterpret_cast<bf16x8*>(
          (char*)Ysh + ((rn1 * 256 + d2) ^ ((rn1 & 7) << 4)));
      int rm0 = m_w + lr, rm1 = m_w + 16 + lr;
      bf16x8 b0 = *reinterpret_cast<bf16x8*>(
          (char*)Xsh[cur] + ((rm0 * 256 + d2) ^ ((rm0 & 7) << 4)));
      bf16x8 b1 = *reinterpret_cast<bf16x8*>(
          (char*)Xsh[cur] + ((rm1 * 256 + d2) ^ ((rm1 & 7) << 4)));
      acc[0][0] = __builtin_amdgcn_mfma_f32_16x16x32_bf16(a0, b0, acc[0][0], 0, 0, 0);
      acc[0][1] = __builtin_amdgcn_mfma_f32_16x16x32_bf16(a0, b1, acc[0][1], 0, 0, 0);
      acc[1][0] = __builtin_amdgcn_mfma_f32_16x16x32_bf16(a1, b0, acc[1][0], 0, 0, 0);
      acc[1][1] = __builtin_amdgcn_mfma_f32_16x16x32_bf16(a1, b1, acc[1][1], 0, 0, 0);
    }

    // Epilogue.
    float sx0 = sqX[b * MXN + mt * 128 + m_w + lr];
    float sx1 = sqX[b * MXN + mt * 128 + m_w + 16 + lr];
#pragma unroll
    for (int i = 0; i < 2; ++i)
#pragma unroll
      for (int reg = 0; reg < 4; ++reg) {
        int n = n0 + i * 16 + ((l >> 4) << 2) + reg;
        size_t obase = ((size_t)b * MXN + n) * MXN + mt * 128 + m_w;
        float v0 = syv[i][reg] + sx0 - 2.0f * acc[i][0][reg];
        float v1 = syv[i][reg] + sx1 - 2.0f * acc[i][1][reg];
        out[obase + lr]      = v0 > 0.f ? v0 : 0.f;
        out[obase + 16 + lr] = v1 > 0.f ? v1 : 0.f;
      }

    // Write next tile into the other buffer (visible after next barrier).
    if (mt < 15) {
#pragma unroll
      for (int i = 0; i < 8; ++i) {
        int ch = i * 256 + t;
        int row = ch >> 4, c = ch & 15;
        int byte = (row * 256 + c * 16) ^ ((row & 7) << 4);
        *reinterpret_cast<bf16x8*>((char*)Xsh[cur ^ 1] + byte) = xr[i];
      }
    }
    cur ^= 1;
  }
}

extern "C" void kernel_launch(void* const* d_in, const int* in_sizes, int n_in,
                              void* d_out, int out_size, void* d_ws, size_t ws_size,
                              hipStream_t stream) {
  const float* X = (const float*)d_in[0];   // (8, 2048, 256)
  const float* Y = (const float*)d_in[1];   // (8, 2048, 256)
  const float* A = (const float*)d_in[2];   // (256, 100)
  float* out = (float*)d_out;               // (8, 2048, 2048)

  char* ws = (char*)d_ws;
  const size_t ROWS = (size_t)NB * MXN;     // 16384
  unsigned short* XAw = (unsigned short*)ws;                        // 4 MB
  unsigned short* YAw = (unsigned short*)(ws + ROWS * KP * 2);      // 4 MB
  float* sqX = (float*)(ws + 2 * ROWS * KP * 2);                    // 64 KB
  float* sqY = (float*)(ws + 2 * ROWS * KP * 2 + ROWS * 4);         // 64 KB
  unsigned short* At = (unsigned short*)(ws + 2 * ROWS * KP * 2 + 2 * ROWS * 4); // 64 KB

  k_At  <<<128, 256, 0, stream>>>(A, At);
  k_proj<<<512, 256, 0, stream>>>(X, Y, At, XAw, YAw, sqX, sqY);
  k_cross<<<512, 256, 0, stream>>>(XAw, YAw, sqX, sqY, out);
}